// Round 7
// baseline (4095.251 us; speedup 1.0000x reference)
//
#include <hip/hip_runtime.h>
#include <stdint.h>

typedef short s16x8 __attribute__((ext_vector_type(8)));
typedef float f32x4 __attribute__((ext_vector_type(4)));

#define LSEG 511

static __device__ __forceinline__ uint32_t cvt_pk_bf16(float lo, float hi) {
  uint32_t r;
  asm("v_cvt_pk_bf16_f32 %0, %1, %2" : "=v"(r) : "v"(lo), "v"(hi));
  return r;
}
static __device__ __forceinline__ unsigned short f2bf(float f) {
  union { float f; uint32_t u; } v; v.f = f;
  uint32_t r = (v.u + 0x7FFFu + ((v.u >> 16) & 1u)) >> 16;
  return (unsigned short)r;
}
static __device__ __forceinline__ float tanh_fast(float x) {
  float ex = __expf(2.f * x);
  return 1.f - 2.f * __builtin_amdgcn_rcpf(ex + 1.f);
}
// DPP cross-lane: xor8 within 16 lanes via row_ror:8 (i^8 == (i+8) mod 16).
static __device__ __forceinline__ float dpp_xor8(float x) {
  return __int_as_float(__builtin_amdgcn_update_dpp(
      0, __float_as_int(x), 0x128, 0xF, 0xF, false));
}

// Role-split kernel: 16 batch rows/block, 8 waves, 1 block/CU.
//  - waves 0-3 (MLP): hold W_in/W_h0/W_h1 frags for a 32-col slice; run
//    P1 (X->H1), P2 (H1->H2), P3 (H2->H1).
//  - waves 4-7 (OUT): hold all W_out frags (c-major permuted cols) + RK
//    state; run P4 (L4 + tanh + einsum + RK + X write).
// Per-wave LDS A-frag reads depend only on M*K, so halving the waves per
// layer halves LDS read traffic (the bottleneck pipe). H tiles use a 4-bit
// XOR block swizzle (phys16B = blk ^ (row&15)); X uses 3-bit.
__global__ __attribute__((amdgpu_flat_work_group_size(512, 512),
                          amdgpu_waves_per_eu(2, 2)))
void cde_kernel(
    const float* __restrict__ coeffs,
    const float* __restrict__ W_init, const float* __restrict__ b_init,
    const float* __restrict__ W_in,  const float* __restrict__ b_in,
    const float* __restrict__ W_h,   const float* __restrict__ b_h,
    const float* __restrict__ W_out, const float* __restrict__ b_out,
    const float* __restrict__ W_read,const float* __restrict__ b_read,
    float* __restrict__ out)
{
  __shared__ __align__(16) char H1mem[16 * 256];
  __shared__ __align__(16) char H2mem[16 * 256];
  __shared__ __align__(16) char Xmem[16 * 128];
  __shared__ float dx2[4][2][16][4];      // [s][hp][row][nt], c = 2*nt+hp

  const int tid  = threadIdx.x;
  const int w    = tid >> 6;       // wave 0..7
  const int lane = tid & 63;
  const int lr   = lane & 15;
  const int lk   = lane >> 4;
  const int lc   = lr & 7;
  const int hp   = lr >> 3;
  const int b0   = blockIdx.x * 16;
  const bool isOut = w >= 4;
  const int ow   = w & 3;          // role-local wave id

  // ---- weight fragments (role-dependent overlay in WF) ----
  s16x8 WF[32];
  f32x4 bin4[2], bh04[2], bh14[2];
  float boutS[8];
  if (!isOut) {
    #pragma unroll
    for (int nt = 0; nt < 2; ++nt) {
      const int col = 32*ow + 16*nt + lr;
      #pragma unroll
      for (int kq = 0; kq < 2; ++kq)
        #pragma unroll
        for (int e = 0; e < 8; ++e)
          WF[kq*2+nt][e] = (short)f2bf(W_in[(32*kq + 8*lk + e)*128 + col]);
      #pragma unroll
      for (int kq = 0; kq < 4; ++kq)
        #pragma unroll
        for (int e = 0; e < 8; ++e) {
          WF[4+kq*2+nt][e]  = (short)f2bf(W_h[(32*kq + 8*lk + e)*128 + col]);
          WF[12+kq*2+nt][e] = (short)f2bf(W_h[16384 + (32*kq + 8*lk + e)*128 + col]);
        }
      const float b1 = b_in[col], b2 = b_h[col], b3 = b_h[128 + col];
      bin4[nt] = (f32x4){b1, b1, b1, b1};
      bh04[nt] = (f32x4){b2, b2, b2, b2};
      bh14[nt] = (f32x4){b3, b3, b3, b3};
    }
  } else {
    #pragma unroll
    for (int nt = 0; nt < 8; ++nt) {
      const int ch = 128*ow + 16*lc + (nt >> 2)*8 + 2*(nt & 3) + hp;
      #pragma unroll
      for (int kq = 0; kq < 4; ++kq)
        #pragma unroll
        for (int e = 0; e < 8; ++e)
          WF[kq*8+nt][e] = (short)f2bf(W_out[(32*kq + 8*lk + e)*512 + ch]);
      boutS[nt] = b_out[ch];
    }
  }

  // ---- precomputed LDS byte offsets ----
  int vb[4];                       // H-tile A-frag reads, row = lr
  #pragma unroll
  for (int kq = 0; kq < 4; ++kq)
    vb[kq] = lr*256 + (((4*kq + lk) ^ (lr & 15)) << 4);
  const int vbX0 = lr*128 + ((lk ^ lc) << 4);
  const int vbX1 = vbX0 ^ 64;
  int wbH[2][4];                   // H writes (MLP), col = 32*ow+16*nt+lr
  #pragma unroll
  for (int nt = 0; nt < 2; ++nt)
    #pragma unroll
    for (int r = 0; r < 4; ++r) {
      const int row = 4*lk + r;
      wbH[nt][r] = row*256 + ((((4*ow + 2*nt + hp) ^ (row & 15)) << 4)) + 2*lc;
    }
  int wbX32[2];                    // X b32 writes (OUT), h pair 16ow+2lc+{0,1}
  #pragma unroll
  for (int j = 0; j < 2; ++j) {
    const int ro = 4*lk + 2*hp + j;
    wbX32[j] = ro*128 + (((2*ow + (lc >> 2)) ^ (ro & 7)) << 4) + 4*(lc & 3);
  }
  const int dbx = hp*256 + lk*64;  // dx2 read base: + s*512 + r*16

  // ---- RK state (OUT waves): rows 4lk+2hp+{0,1}, h = 16ow+2lc+{0,1} ----
  float z0[2][2], zfin[2][2], k1r[2][2], k2r[2][2];
  if (isOut) {
    #pragma unroll
    for (int j = 0; j < 2; ++j) {
      const int ro = 4*lk + 2*hp + j;
      const float* a0r = &coeffs[(size_t)(b0 + ro) * (LSEG*32)];
      #pragma unroll
      for (int m = 0; m < 2; ++m) {
        const int h = 16*ow + 2*lc + m;
        float sv = b_init[h];
        #pragma unroll
        for (int c = 0; c < 8; ++c) sv = fmaf(a0r[c], W_init[c*64 + h], sv);
        z0[j][m] = sv; zfin[j][m] = 0.f; k1r[j][m] = 0.f; k2r[j][m] = 0.f;
      }
      *(uint32_t*)(Xmem + wbX32[j]) = cvt_pk_bf16(z0[j][0], z0[j][1]);
    }
  }

  // ---- coeff prefetch regs (MLP waves, 32 active lanes each) ----
  float cf_b = 0.f, cf_c = 0.f, cf_d = 0.f;
  const int cidx = lane >> 1;
  const int crow = 4*ow + (cidx >> 3);
  const int ccc  = cidx & 7;
  const bool cact = (!isOut) && ((lane & 1) == 0);
  if (cact) {
    const float* cp = &coeffs[(size_t)(b0 + crow)*(LSEG*32)];
    cf_b = cp[8+ccc]; cf_c = cp[16+ccc]; cf_d = cp[24+ccc];
  }
  __syncthreads();

  #pragma unroll 1
  for (int t = 0; t < LSEG; ++t) {
    #pragma unroll
    for (int s = 0; s < 4; ++s) {
      // ============ P1 (MLP): dx2 @ s==0, then L1: X -> H1 ============
      if (!isOut) {
        if (s == 0 && cact) {
          const float third = 1.f/3.f, two3 = 2.f/3.f;
          const int dxo = (ccc & 1)*256 + crow*16 + (ccc >> 1)*4;
          *(float*)((char*)dx2 + dxo)        = cf_b;
          *(float*)((char*)dx2 + dxo + 512)  = fmaf(fmaf(cf_d, third, cf_c), third, cf_b);
          *(float*)((char*)dx2 + dxo + 1024) = fmaf(fmaf(cf_d, two3, cf_c), two3, cf_b);
          *(float*)((char*)dx2 + dxo + 1536) = cf_b + cf_c + cf_d;
          if (t + 1 < LSEG) {
            const float* cp = &coeffs[((size_t)(b0 + crow)*LSEG + (t+1))*32];
            cf_b = cp[8+ccc]; cf_c = cp[16+ccc]; cf_d = cp[24+ccc];
          }
        }
        s16x8 a0 = *(const s16x8*)(Xmem + vbX0);
        s16x8 a1 = *(const s16x8*)(Xmem + vbX1);
        #pragma unroll
        for (int nt = 0; nt < 2; ++nt) {
          f32x4 acc = __builtin_amdgcn_mfma_f32_16x16x32_bf16(a0, WF[nt],   bin4[nt], 0, 0, 0);
          acc       = __builtin_amdgcn_mfma_f32_16x16x32_bf16(a1, WF[2+nt], acc,      0, 0, 0);
          #pragma unroll
          for (int r = 0; r < 4; ++r) {
            float v = fmaxf(acc[r], 0.f);
            *(unsigned short*)(H1mem + wbH[nt][r]) = (unsigned short)cvt_pk_bf16(v, v);
          }
        }
      }
      __syncthreads();

      // ============ P2 (MLP): L2: H1 -> H2 ============
      if (!isOut) {
        s16x8 a0 = *(const s16x8*)(H1mem + vb[0]);
        s16x8 a1 = *(const s16x8*)(H1mem + vb[1]);
        s16x8 a2 = *(const s16x8*)(H1mem + vb[2]);
        s16x8 a3 = *(const s16x8*)(H1mem + vb[3]);
        #pragma unroll
        for (int nt = 0; nt < 2; ++nt) {
          f32x4 acc = __builtin_amdgcn_mfma_f32_16x16x32_bf16(a0, WF[4+nt],  bh04[nt], 0, 0, 0);
          acc       = __builtin_amdgcn_mfma_f32_16x16x32_bf16(a1, WF[6+nt],  acc, 0, 0, 0);
          acc       = __builtin_amdgcn_mfma_f32_16x16x32_bf16(a2, WF[8+nt],  acc, 0, 0, 0);
          acc       = __builtin_amdgcn_mfma_f32_16x16x32_bf16(a3, WF[10+nt], acc, 0, 0, 0);
          #pragma unroll
          for (int r = 0; r < 4; ++r) {
            float v = fmaxf(acc[r], 0.f);
            *(unsigned short*)(H2mem + wbH[nt][r]) = (unsigned short)cvt_pk_bf16(v, v);
          }
        }
      }
      __syncthreads();

      // ============ P3 (MLP): L3: H2 -> H1 ============
      if (!isOut) {
        s16x8 a0 = *(const s16x8*)(H2mem + vb[0]);
        s16x8 a1 = *(const s16x8*)(H2mem + vb[1]);
        s16x8 a2 = *(const s16x8*)(H2mem + vb[2]);
        s16x8 a3 = *(const s16x8*)(H2mem + vb[3]);
        #pragma unroll
        for (int nt = 0; nt < 2; ++nt) {
          f32x4 acc = __builtin_amdgcn_mfma_f32_16x16x32_bf16(a0, WF[12+nt], bh14[nt], 0, 0, 0);
          acc       = __builtin_amdgcn_mfma_f32_16x16x32_bf16(a1, WF[14+nt], acc, 0, 0, 0);
          acc       = __builtin_amdgcn_mfma_f32_16x16x32_bf16(a2, WF[16+nt], acc, 0, 0, 0);
          acc       = __builtin_amdgcn_mfma_f32_16x16x32_bf16(a3, WF[18+nt], acc, 0, 0, 0);
          #pragma unroll
          for (int r = 0; r < 4; ++r) {
            float v = fmaxf(acc[r], 0.f);
            *(unsigned short*)(H1mem + wbH[nt][r]) = (unsigned short)cvt_pk_bf16(v, v);
          }
        }
      }
      __syncthreads();

      // ====== P4 (OUT): L4 + tanh + einsum + RK state + X write ======
      if (isOut) {
        f32x4 dxv[4];
        #pragma unroll
        for (int r = 0; r < 4; ++r)
          dxv[r] = *(const f32x4*)((const char*)dx2 + dbx + s*512 + r*16);
        s16x8 a0 = *(const s16x8*)(H1mem + vb[0]);
        s16x8 a1 = *(const s16x8*)(H1mem + vb[1]);
        s16x8 a2 = *(const s16x8*)(H1mem + vb[2]);
        s16x8 a3 = *(const s16x8*)(H1mem + vb[3]);
        const f32x4 fz = {0.f, 0.f, 0.f, 0.f};
        float sumA[4], sumB[4];
        {  // m = 0 half (h even): frag cols nt 0..3, c = 2*nt + hp
          f32x4 acc[4];
          #pragma unroll
          for (int nt = 0; nt < 4; ++nt) {
            f32x4 tacc = __builtin_amdgcn_mfma_f32_16x16x32_bf16(a0, WF[nt],    fz,   0, 0, 0);
            tacc       = __builtin_amdgcn_mfma_f32_16x16x32_bf16(a1, WF[8+nt],  tacc, 0, 0, 0);
            tacc       = __builtin_amdgcn_mfma_f32_16x16x32_bf16(a2, WF[16+nt], tacc, 0, 0, 0);
            acc[nt]    = __builtin_amdgcn_mfma_f32_16x16x32_bf16(a3, WF[24+nt], tacc, 0, 0, 0);
          }
          #pragma unroll
          for (int r = 0; r < 4; ++r) {
            float sv = 0.f;
            #pragma unroll
            for (int nt = 0; nt < 4; ++nt)
              sv = fmaf(tanh_fast(acc[nt][r] + boutS[nt]), dxv[r][nt], sv);
            sumA[r] = sv + dpp_xor8(sv);
          }
        }
        {  // m = 1 half (h odd): frag cols nt 4..7
          f32x4 acc[4];
          #pragma unroll
          for (int nt = 0; nt < 4; ++nt) {
            f32x4 tacc = __builtin_amdgcn_mfma_f32_16x16x32_bf16(a0, WF[4+nt],  fz,   0, 0, 0);
            tacc       = __builtin_amdgcn_mfma_f32_16x16x32_bf16(a1, WF[12+nt], tacc, 0, 0, 0);
            tacc       = __builtin_amdgcn_mfma_f32_16x16x32_bf16(a2, WF[20+nt], tacc, 0, 0, 0);
            acc[nt]    = __builtin_amdgcn_mfma_f32_16x16x32_bf16(a3, WF[28+nt], tacc, 0, 0, 0);
          }
          #pragma unroll
          for (int r = 0; r < 4; ++r) {
            float sv = 0.f;
            #pragma unroll
            for (int nt = 0; nt < 4; ++nt)
              sv = fmaf(tanh_fast(acc[nt][r] + boutS[4+nt]), dxv[r][nt], sv);
            sumB[r] = sv + dpp_xor8(sv);
          }
        }
        #pragma unroll
        for (int j = 0; j < 2; ++j) {
          float zn[2];
          #pragma unroll
          for (int m = 0; m < 2; ++m) {
            const float s0 = hp ? (m ? sumB[2+j] : sumA[2+j])
                                : (m ? sumB[j]   : sumA[j]);
            if (s == 0) {
              k1r[j][m] = s0;
              zfin[j][m] = fmaf(0.125f, s0, z0[j][m]);
              zn[m]      = fmaf(1.f/3.f, s0, z0[j][m]);
            } else if (s == 1) {
              k2r[j][m] = s0;
              zfin[j][m] = fmaf(0.375f, s0, zfin[j][m]);
              zn[m]      = z0[j][m] + s0 - (1.f/3.f)*k1r[j][m];
            } else if (s == 2) {
              zfin[j][m] = fmaf(0.375f, s0, zfin[j][m]);
              zn[m]      = z0[j][m] + k1r[j][m] - k2r[j][m] + s0;
            } else {
              zfin[j][m] = fmaf(0.125f, s0, zfin[j][m]);
              zn[m]      = zfin[j][m];
              z0[j][m]   = zfin[j][m];
            }
          }
          *(uint32_t*)(Xmem + wbX32[j]) = cvt_pk_bf16(zn[0], zn[1]);
        }
      }
      __syncthreads();
    }
  }

  // ---- readout: OUT waves stage z0 (fp32) into H1 bytes, dot W_read ----
  float* ZF = (float*)H1mem;   // plain [16][64] floats
  if (isOut) {
    #pragma unroll
    for (int j = 0; j < 2; ++j)
      #pragma unroll
      for (int m = 0; m < 2; ++m)
        ZF[(4*lk + 2*hp + j)*64 + 16*ow + 2*lc + m] = z0[j][m];
  }
  __syncthreads();
  if (tid < 16) {
    float acc = b_read[0];
    for (int h = 0; h < 64; ++h) acc = fmaf(ZF[tid*64 + h], W_read[h], acc);
    out[b0 + tid] = acc;
  }
}

extern "C" void kernel_launch(void* const* d_in, const int* in_sizes, int n_in,
                              void* d_out, int out_size, void* d_ws, size_t ws_size,
                              hipStream_t stream) {
  const float* coeffs = (const float*)d_in[0];
  const float* W_init = (const float*)d_in[1];
  const float* b_init = (const float*)d_in[2];
  const float* W_in   = (const float*)d_in[3];
  const float* b_in   = (const float*)d_in[4];
  const float* W_h    = (const float*)d_in[5];
  const float* b_h    = (const float*)d_in[6];
  const float* W_out  = (const float*)d_in[7];
  const float* b_out  = (const float*)d_in[8];
  const float* W_read = (const float*)d_in[9];
  const float* b_read = (const float*)d_in[10];
  float* out = (float*)d_out;

  cde_kernel<<<dim3(256), dim3(512), 0, stream>>>(
      coeffs, W_init, b_init, W_in, b_in, W_h, b_h, W_out, b_out,
      W_read, b_read, out);
}

// Round 8
// 3099.715 us; speedup vs baseline: 1.3212x; 1.3212x over previous
//
#include <hip/hip_runtime.h>
#include <stdint.h>

typedef short s16x8 __attribute__((ext_vector_type(8)));
typedef float f32x4 __attribute__((ext_vector_type(4)));

#define LSEG 511

static __device__ __forceinline__ uint32_t cvt_pk_bf16(float lo, float hi) {
  uint32_t r;
  asm("v_cvt_pk_bf16_f32 %0, %1, %2" : "=v"(r) : "v"(lo), "v"(hi));
  return r;
}
static __device__ __forceinline__ unsigned short f2bf(float f) {
  union { float f; uint32_t u; } v; v.f = f;
  uint32_t r = (v.u + 0x7FFFu + ((v.u >> 16) & 1u)) >> 16;
  return (unsigned short)r;
}
static __device__ __forceinline__ float tanh_fast(float x) {
  float ex = __expf(2.f * x);
  return 1.f - 2.f * __builtin_amdgcn_rcpf(ex + 1.f);
}
// DPP cross-lane (VALU pipe): xor1 via quad_perm[1,0,3,2]=0xB1,
// xor8-within-16 via row_ror:8=0x128 (i^8 == (i+8) mod 16).
static __device__ __forceinline__ float dpp_xor1(float x) {
  return __int_as_float(__builtin_amdgcn_update_dpp(
      0, __float_as_int(x), 0xB1, 0xF, 0xF, false));
}
static __device__ __forceinline__ float dpp_xor8(float x) {
  return __int_as_float(__builtin_amdgcn_update_dpp(
      0, __float_as_int(x), 0x128, 0xF, 0xF, false));
}

// 16 batch rows/block, 8 ALL-ACTIVE waves, 1 block/CU (2 waves/SIMD so
// co-resident waves hide each other's LDS/barrier stalls — R6 showed
// 1 active wave/SIMD costs ~+35%).
// Per RK stage 4 phases/barriers:
// [P1: X->H1] [P2: H1->H2] [P3: H2->H1] [P4: H1 -> f -> einsum -> RK -> X]
// RK state (z0, zfin, k1, k2) lives in einsum-holder lane registers via the
// c-major W_out column permutation (ch = 64w + 8*lc + 2*nt + hp).
// LDS: 4-bit XOR block swizzle on H (phys16B = blk ^ row), 3-bit on X;
// ALL epilogue writes are paired b32 (cvt_pk + dpp_xor1, even lanes) ->
// 2-way-free bank pattern and half the write transactions.
__global__ __attribute__((amdgpu_flat_work_group_size(512, 512),
                          amdgpu_waves_per_eu(2, 2)))
void cde_kernel(
    const float* __restrict__ coeffs,
    const float* __restrict__ W_init, const float* __restrict__ b_init,
    const float* __restrict__ W_in,  const float* __restrict__ b_in,
    const float* __restrict__ W_h,   const float* __restrict__ b_h,
    const float* __restrict__ W_out, const float* __restrict__ b_out,
    const float* __restrict__ W_read,const float* __restrict__ b_read,
    float* __restrict__ out)
{
  __shared__ __align__(16) char H1mem[16 * 256];
  __shared__ __align__(16) char H2mem[16 * 256];
  __shared__ __align__(16) char Xmem[16 * 128];
  __shared__ float dx2[4][2][16][4];      // [s][hp][row][nt], c = 2*nt+hp

  const int tid  = threadIdx.x;
  const int w    = tid >> 6;     // wave 0..7
  const int lane = tid & 63;
  const int lr   = lane & 15;
  const int lk   = lane >> 4;
  const int lc   = lr & 7;
  const int hp   = lr >> 3;
  const int b0   = blockIdx.x * 16;
  const int h_own = 8*w + lc;    // this lane's h in the einsum

  // ---- weight fragments (B layout: elem e = W[32*kq+8*lk+e][col]) ----
  s16x8 Win_f[2], Wh0_f[4], Wh1_f[4], Wout_f[4][4];
  const int wc = 16*w + lr;      // L1-3 col
  #pragma unroll
  for (int kq = 0; kq < 2; ++kq)
    #pragma unroll
    for (int e = 0; e < 8; ++e)
      Win_f[kq][e] = (short)f2bf(W_in[(32*kq + 8*lk + e)*128 + wc]);
  #pragma unroll
  for (int kq = 0; kq < 4; ++kq)
    #pragma unroll
    for (int e = 0; e < 8; ++e) {
      Wh0_f[kq][e] = (short)f2bf(W_h[(32*kq + 8*lk + e)*128 + wc]);
      Wh1_f[kq][e] = (short)f2bf(W_h[16384 + (32*kq + 8*lk + e)*128 + wc]);
    }
  #pragma unroll
  for (int kq = 0; kq < 4; ++kq)
    #pragma unroll
    for (int nt = 0; nt < 4; ++nt) {
      const int ch = 64*w + 8*lc + 2*nt + hp;   // c-major permutation
      #pragma unroll
      for (int e = 0; e < 8; ++e)
        Wout_f[kq][nt][e] = (short)f2bf(W_out[(32*kq + 8*lk + e)*512 + ch]);
    }
  // bias splats for MFMA C-in folding
  const float binv = b_in[wc];
  const float bh0v = b_h[wc];
  const float bh1v = b_h[128 + wc];
  const f32x4 bin4 = {binv, binv, binv, binv};
  const f32x4 bh04 = {bh0v, bh0v, bh0v, bh0v};
  const f32x4 bh14 = {bh1v, bh1v, bh1v, bh1v};
  f32x4 bout4[4];
  #pragma unroll
  for (int nt = 0; nt < 4; ++nt) {
    const float b = b_out[64*w + 8*lc + 2*nt + hp];
    bout4[nt] = (f32x4){b, b, b, b};
  }

  // ---- precomputed LDS byte offsets (loop-invariant per lane) ----
  int vb[4];                       // H A-frag reads: row = lr, 4-bit swizzle
  #pragma unroll
  for (int kq = 0; kq < 4; ++kq)
    vb[kq] = lr*256 + (((4*kq + lk) ^ lr) << 4);
  const int vbX0 = lr*128 + ((lk ^ lc) << 4);
  const int vbX1 = vbX0 ^ 64;
  int wbH32[4];                    // paired H writes (even lr): cols wc, wc+1
  #pragma unroll
  for (int r = 0; r < 4; ++r) {
    const int row = 4*lk + r;
    wbH32[r] = row*256 + (((2*w + hp) ^ row) << 4) + ((lr & 7) << 1);
  }
  int wbX32[2];                    // paired X writes (even lc): h, h+1
  #pragma unroll
  for (int j = 0; j < 2; ++j) {
    const int ro = 4*lk + 2*hp + j;
    wbX32[j] = ro*128 + ((w ^ (ro & 7)) << 4) + (lc << 1);
  }
  const int dbx = hp*256 + lk*64;  // dx2 read base: + s*512 + r*16

  // ---- z0 init: lane owns rows 4lk+2hp+{0,1}, channel h_own ----
  float z0[2], zfin[2], k1r[2], k2r[2];
  {
    float Wi[8];
    #pragma unroll
    for (int c = 0; c < 8; ++c) Wi[c] = W_init[c*64 + h_own];
    const float bi = b_init[h_own];
    #pragma unroll
    for (int j = 0; j < 2; ++j) {
      const int ro = 4*lk + 2*hp + j;
      const float* a0r = &coeffs[(size_t)(b0 + ro) * (LSEG*32)];
      float s = bi;
      #pragma unroll
      for (int c = 0; c < 8; ++c) s = fmaf(a0r[c], Wi[c], s);
      z0[j] = s; zfin[j] = 0.f; k1r[j] = 0.f; k2r[j] = 0.f;
    }
    uint32_t pk0 = cvt_pk_bf16(z0[0], dpp_xor1(z0[0]));
    uint32_t pk1 = cvt_pk_bf16(z0[1], dpp_xor1(z0[1]));
    if ((lc & 1) == 0) {
      *(uint32_t*)(Xmem + wbX32[0]) = pk0;
      *(uint32_t*)(Xmem + wbX32[1]) = pk1;
    }
  }

  // ---- coeff prefetch regs (lanes with (lane&3)==0 in every wave... keep
  //      R5 mapping: tid<128 lanes, 16 rows x 8 c) ----
  float cf_b = 0.f, cf_c = 0.f, cf_d = 0.f;
  const int crow = tid >> 3, ccc = tid & 7;
  const bool cact = tid < 128;
  if (cact) {
    const float* cp = &coeffs[(size_t)(b0 + crow)*(LSEG*32)];
    cf_b = cp[8+ccc]; cf_c = cp[16+ccc]; cf_d = cp[24+ccc];
  }
  __syncthreads();

  #pragma unroll 1
  for (int t = 0; t < LSEG; ++t) {
    #pragma unroll
    for (int s = 0; s < 4; ++s) {
      // =============== P1: (dx2 @ s==0) + L1: X -> H1 ===============
      if (s == 0 && cact) {
        const float third = 1.f/3.f, two3 = 2.f/3.f;
        const int dxo = (ccc & 1)*256 + crow*16 + (ccc >> 1)*4;
        *(float*)((char*)dx2 + dxo)        = cf_b;
        *(float*)((char*)dx2 + dxo + 512)  = fmaf(fmaf(cf_d, third, cf_c), third, cf_b);
        *(float*)((char*)dx2 + dxo + 1024) = fmaf(fmaf(cf_d, two3, cf_c), two3, cf_b);
        *(float*)((char*)dx2 + dxo + 1536) = cf_b + cf_c + cf_d;
        if (t + 1 < LSEG) {
          const float* cp = &coeffs[((size_t)(b0 + crow)*LSEG + (t+1))*32];
          cf_b = cp[8+ccc]; cf_c = cp[16+ccc]; cf_d = cp[24+ccc];
        }
      }
      {
        s16x8 a0 = *(const s16x8*)(Xmem + vbX0);
        s16x8 a1 = *(const s16x8*)(Xmem + vbX1);
        f32x4 acc;
        acc = __builtin_amdgcn_mfma_f32_16x16x32_bf16(a0, Win_f[0], bin4, 0, 0, 0);
        acc = __builtin_amdgcn_mfma_f32_16x16x32_bf16(a1, Win_f[1], acc, 0, 0, 0);
        uint32_t pk[4];
        #pragma unroll
        for (int r = 0; r < 4; ++r) {
          float v = fmaxf(acc[r], 0.f);
          pk[r] = cvt_pk_bf16(v, dpp_xor1(v));
        }
        if ((lr & 1) == 0) {
          #pragma unroll
          for (int r = 0; r < 4; ++r)
            *(uint32_t*)(H1mem + wbH32[r]) = pk[r];
        }
      }
      __syncthreads();

      // =============== P2: L2: H1 -> H2 ===============
      {
        s16x8 a0 = *(const s16x8*)(H1mem + vb[0]);
        s16x8 a1 = *(const s16x8*)(H1mem + vb[1]);
        s16x8 a2 = *(const s16x8*)(H1mem + vb[2]);
        s16x8 a3 = *(const s16x8*)(H1mem + vb[3]);
        f32x4 acc0, acc1 = {};
        acc0 = __builtin_amdgcn_mfma_f32_16x16x32_bf16(a0, Wh0_f[0], bh04, 0, 0, 0);
        acc1 = __builtin_amdgcn_mfma_f32_16x16x32_bf16(a1, Wh0_f[1], acc1, 0, 0, 0);
        acc0 = __builtin_amdgcn_mfma_f32_16x16x32_bf16(a2, Wh0_f[2], acc0, 0, 0, 0);
        acc1 = __builtin_amdgcn_mfma_f32_16x16x32_bf16(a3, Wh0_f[3], acc1, 0, 0, 0);
        f32x4 acc = acc0 + acc1;
        uint32_t pk[4];
        #pragma unroll
        for (int r = 0; r < 4; ++r) {
          float v = fmaxf(acc[r], 0.f);
          pk[r] = cvt_pk_bf16(v, dpp_xor1(v));
        }
        if ((lr & 1) == 0) {
          #pragma unroll
          for (int r = 0; r < 4; ++r)
            *(uint32_t*)(H2mem + wbH32[r]) = pk[r];
        }
      }
      __syncthreads();

      // =============== P3: L3: H2 -> H1 ===============
      {
        s16x8 a0 = *(const s16x8*)(H2mem + vb[0]);
        s16x8 a1 = *(const s16x8*)(H2mem + vb[1]);
        s16x8 a2 = *(const s16x8*)(H2mem + vb[2]);
        s16x8 a3 = *(const s16x8*)(H2mem + vb[3]);
        f32x4 acc0, acc1 = {};
        acc0 = __builtin_amdgcn_mfma_f32_16x16x32_bf16(a0, Wh1_f[0], bh14, 0, 0, 0);
        acc1 = __builtin_amdgcn_mfma_f32_16x16x32_bf16(a1, Wh1_f[1], acc1, 0, 0, 0);
        acc0 = __builtin_amdgcn_mfma_f32_16x16x32_bf16(a2, Wh1_f[2], acc0, 0, 0, 0);
        acc1 = __builtin_amdgcn_mfma_f32_16x16x32_bf16(a3, Wh1_f[3], acc1, 0, 0, 0);
        f32x4 acc = acc0 + acc1;
        uint32_t pk[4];
        #pragma unroll
        for (int r = 0; r < 4; ++r) {
          float v = fmaxf(acc[r], 0.f);
          pk[r] = cvt_pk_bf16(v, dpp_xor1(v));
        }
        if ((lr & 1) == 0) {
          #pragma unroll
          for (int r = 0; r < 4; ++r)
            *(uint32_t*)(H1mem + wbH32[r]) = pk[r];
        }
      }
      __syncthreads();

      // ========= P4: L4 + tanh + einsum + RK state + X write =========
      {
        f32x4 dxv[4];
        #pragma unroll
        for (int r = 0; r < 4; ++r)
          dxv[r] = *(const f32x4*)((const char*)dx2 + dbx + s*512 + r*16);
        s16x8 a0 = *(const s16x8*)(H1mem + vb[0]);
        s16x8 a1 = *(const s16x8*)(H1mem + vb[1]);
        s16x8 a2 = *(const s16x8*)(H1mem + vb[2]);
        s16x8 a3 = *(const s16x8*)(H1mem + vb[3]);
        f32x4 acc[4];
        #pragma unroll
        for (int nt = 0; nt < 4; ++nt)
          acc[nt] = __builtin_amdgcn_mfma_f32_16x16x32_bf16(a0, Wout_f[0][nt], bout4[nt], 0, 0, 0);
        #pragma unroll
        for (int nt = 0; nt < 4; ++nt)
          acc[nt] = __builtin_amdgcn_mfma_f32_16x16x32_bf16(a1, Wout_f[1][nt], acc[nt], 0, 0, 0);
        #pragma unroll
        for (int nt = 0; nt < 4; ++nt)
          acc[nt] = __builtin_amdgcn_mfma_f32_16x16x32_bf16(a2, Wout_f[2][nt], acc[nt], 0, 0, 0);
        #pragma unroll
        for (int nt = 0; nt < 4; ++nt)
          acc[nt] = __builtin_amdgcn_mfma_f32_16x16x32_bf16(a3, Wout_f[3][nt], acc[nt], 0, 0, 0);
        float sums[4];
        #pragma unroll
        for (int r = 0; r < 4; ++r) {
          float sum = 0.f;
          #pragma unroll
          for (int nt = 0; nt < 4; ++nt)
            sum = fmaf(tanh_fast(acc[nt][r]), dxv[r][nt], sum);
          sums[r] = sum + dpp_xor8(sum);   // full c-sum on both hp halves
        }
        float zn[2];
        #pragma unroll
        for (int j = 0; j < 2; ++j) {
          const float sum = sums[2*hp + j];
          if (s == 0) {
            k1r[j] = sum;
            zfin[j] = fmaf(0.125f, sum, z0[j]);
            zn[j]   = fmaf(1.f/3.f, sum, z0[j]);
          } else if (s == 1) {
            k2r[j] = sum;
            zfin[j] = fmaf(0.375f, sum, zfin[j]);
            zn[j]   = z0[j] + sum - (1.f/3.f)*k1r[j];
          } else if (s == 2) {
            zfin[j] = fmaf(0.375f, sum, zfin[j]);
            zn[j]   = z0[j] + k1r[j] - k2r[j] + sum;
          } else {
            zfin[j] = fmaf(0.125f, sum, zfin[j]);
            zn[j]   = zfin[j];
            z0[j]   = zfin[j];
          }
        }
        uint32_t pk0 = cvt_pk_bf16(zn[0], dpp_xor1(zn[0]));
        uint32_t pk1 = cvt_pk_bf16(zn[1], dpp_xor1(zn[1]));
        if ((lc & 1) == 0) {
          *(uint32_t*)(Xmem + wbX32[0]) = pk0;
          *(uint32_t*)(Xmem + wbX32[1]) = pk1;
        }
      }
      __syncthreads();
    }
  }

  // ---- readout: stage z0 (fp32) into H1 bytes, then dot W_read ----
  float* ZF = (float*)H1mem;   // plain [16][64] floats
  #pragma unroll
  for (int j = 0; j < 2; ++j)
    ZF[(4*lk + 2*hp + j)*64 + h_own] = z0[j];
  __syncthreads();
  if (tid < 16) {
    float acc = b_read[0];
    for (int h = 0; h < 64; ++h) acc = fmaf(ZF[tid*64 + h], W_read[h], acc);
    out[b0 + tid] = acc;
  }
}

extern "C" void kernel_launch(void* const* d_in, const int* in_sizes, int n_in,
                              void* d_out, int out_size, void* d_ws, size_t ws_size,
                              hipStream_t stream) {
  const float* coeffs = (const float*)d_in[0];
  const float* W_init = (const float*)d_in[1];
  const float* b_init = (const float*)d_in[2];
  const float* W_in   = (const float*)d_in[3];
  const float* b_in   = (const float*)d_in[4];
  const float* W_h    = (const float*)d_in[5];
  const float* b_h    = (const float*)d_in[6];
  const float* W_out  = (const float*)d_in[7];
  const float* b_out  = (const float*)d_in[8];
  const float* W_read = (const float*)d_in[9];
  const float* b_read = (const float*)d_in[10];
  float* out = (float*)d_out;

  cde_kernel<<<dim3(256), dim3(512), 0, stream>>>(
      coeffs, W_init, b_init, W_in, b_in, W_h, b_h, W_out, b_out,
      W_read, b_read, out);
}

// Round 9
// 2827.848 us; speedup vs baseline: 1.4482x; 1.0961x over previous
//
#include <hip/hip_runtime.h>
#include <stdint.h>

typedef short s16x8 __attribute__((ext_vector_type(8)));
typedef float f32x4 __attribute__((ext_vector_type(4)));

#define LSEG 511

static __device__ __forceinline__ uint32_t cvt_pk_bf16(float lo, float hi) {
  uint32_t r;
  asm("v_cvt_pk_bf16_f32 %0, %1, %2" : "=v"(r) : "v"(lo), "v"(hi));
  return r;
}
static __device__ __forceinline__ unsigned short f2bf(float f) {
  union { float f; uint32_t u; } v; v.f = f;
  uint32_t r = (v.u + 0x7FFFu + ((v.u >> 16) & 1u)) >> 16;
  return (unsigned short)r;
}
// DPP cross-lane: xor8 within 16 lanes via row_ror:8 (i^8 == (i+8) mod 16).
static __device__ __forceinline__ float dpp_xor8(float x) {
  return __int_as_float(__builtin_amdgcn_update_dpp(
      0, __float_as_int(x), 0x128, 0xF, 0xF, false));
}

// 16 batch rows/block, 8 all-active waves, 1 block/CU (2 waves/SIMD).
// R5 structure (best measured): 4 phases/RK-stage, 3-bit XOR swizzle,
// plain b16 epilogue writes, precomputed per-lane LDS byte offsets.
// This round: W_out/b_out pre-scaled by 2*log2(e) so tanh is
// 1 - 2*rcp(exp2(acc)+1) directly off the accumulator; dx2 prep spread
// over all 8 waves; s_setprio(1) around MFMA clusters.
__global__ __attribute__((amdgpu_flat_work_group_size(512, 512),
                          amdgpu_waves_per_eu(2, 2)))
void cde_kernel(
    const float* __restrict__ coeffs,
    const float* __restrict__ W_init, const float* __restrict__ b_init,
    const float* __restrict__ W_in,  const float* __restrict__ b_in,
    const float* __restrict__ W_h,   const float* __restrict__ b_h,
    const float* __restrict__ W_out, const float* __restrict__ b_out,
    const float* __restrict__ W_read,const float* __restrict__ b_read,
    float* __restrict__ out)
{
  __shared__ __align__(16) char H1mem[16 * 256];
  __shared__ __align__(16) char H2mem[16 * 256];
  __shared__ __align__(16) char Xmem[16 * 128];
  __shared__ float dx2[4][2][16][4];      // [s][hp][row][nt], c = 2*nt+hp

  const int tid  = threadIdx.x;
  const int w    = tid >> 6;     // wave 0..7
  const int lane = tid & 63;
  const int lr   = lane & 15;
  const int lk   = lane >> 4;
  const int lc   = lr & 7;
  const int hp   = lr >> 3;
  const int b0   = blockIdx.x * 16;
  const int h_own = 8*w + lc;    // this lane's h in the einsum

  const float TS = 2.8853900817779268f;   // 2*log2(e)

  // ---- weight fragments (B layout: elem e = W[32*kq+8*lk+e][col]) ----
  s16x8 Win_f[2], Wh0_f[4], Wh1_f[4], Wout_f[4][4];
  const int wc = 16*w + lr;      // L1-3 col
  #pragma unroll
  for (int kq = 0; kq < 2; ++kq)
    #pragma unroll
    for (int e = 0; e < 8; ++e)
      Win_f[kq][e] = (short)f2bf(W_in[(32*kq + 8*lk + e)*128 + wc]);
  #pragma unroll
  for (int kq = 0; kq < 4; ++kq)
    #pragma unroll
    for (int e = 0; e < 8; ++e) {
      Wh0_f[kq][e] = (short)f2bf(W_h[(32*kq + 8*lk + e)*128 + wc]);
      Wh1_f[kq][e] = (short)f2bf(W_h[16384 + (32*kq + 8*lk + e)*128 + wc]);
    }
  #pragma unroll
  for (int kq = 0; kq < 4; ++kq)
    #pragma unroll
    for (int nt = 0; nt < 4; ++nt) {
      const int ch = 64*w + 8*lc + 2*nt + hp;   // c-major permutation
      #pragma unroll
      for (int e = 0; e < 8; ++e)
        Wout_f[kq][nt][e] = (short)f2bf(W_out[(32*kq + 8*lk + e)*512 + ch] * TS);
    }
  // bias splats for MFMA C-in folding
  const float binv = b_in[wc];
  const float bh0v = b_h[wc];
  const float bh1v = b_h[128 + wc];
  const f32x4 bin4 = {binv, binv, binv, binv};
  const f32x4 bh04 = {bh0v, bh0v, bh0v, bh0v};
  const f32x4 bh14 = {bh1v, bh1v, bh1v, bh1v};
  f32x4 bout4[4];
  #pragma unroll
  for (int nt = 0; nt < 4; ++nt) {
    const float b = b_out[64*w + 8*lc + 2*nt + hp] * TS;
    bout4[nt] = (f32x4){b, b, b, b};
  }

  // ---- precomputed LDS byte offsets (loop-invariant per lane) ----
  const int r2  = (lr >> 2) & 1;
  const int vbHe = lr*256 + (((lk ^ lr) & 3) << 4) + (r2 << 6);
  const int vbHo = lr*256 + (((lk ^ lr) & 3) << 4) + ((1 ^ r2) << 6);
  const int vbX0 = lr*128 + ((lk ^ (lr & 7)) << 4);
  const int vbX1 = vbX0 ^ 64;
  int wbH[4];
  #pragma unroll
  for (int r = 0; r < 4; ++r) {
    const int row = 4*lk + r;
    wbH[r] = row*256 + ((((2*w + (lr >> 3)) ^ (row & 7)) << 4)) + ((lr & 7) << 1);
  }
  int wbX[2];
  #pragma unroll
  for (int j = 0; j < 2; ++j) {
    const int ro = 4*lk + 2*hp + j;
    wbX[j] = ro*128 + (((w ^ (ro & 7)) << 4)) + (lc << 1);
  }
  const int dbx = hp*256 + lk*64;  // dx2 read base: + s*512 + r*16

  // ---- z0 init: lane owns rows 4lk+2hp+{0,1}, channel h_own ----
  float z0[2], zfin[2], k1r[2], k2r[2];
  {
    float Wi[8];
    #pragma unroll
    for (int c = 0; c < 8; ++c) Wi[c] = W_init[c*64 + h_own];
    const float bi = b_init[h_own];
    #pragma unroll
    for (int j = 0; j < 2; ++j) {
      const int ro = 4*lk + 2*hp + j;
      const float* a0r = &coeffs[(size_t)(b0 + ro) * (LSEG*32)];
      float s = bi;
      #pragma unroll
      for (int c = 0; c < 8; ++c) s = fmaf(a0r[c], Wi[c], s);
      z0[j] = s; zfin[j] = 0.f; k1r[j] = 0.f; k2r[j] = 0.f;
      *(unsigned short*)(Xmem + wbX[j]) = f2bf(s);
    }
  }

  // ---- coeff prefetch regs: 16 lanes per wave (lane&3)==0, 2 rows/wave ----
  float cf_b = 0.f, cf_c = 0.f, cf_d = 0.f;
  const int crow = 2*w + (lane >> 5);
  const int ccc  = (lane >> 2) & 7;
  const bool cact = (lane & 3) == 0;
  if (cact) {
    const float* cp = &coeffs[(size_t)(b0 + crow)*(LSEG*32)];
    cf_b = cp[8+ccc]; cf_c = cp[16+ccc]; cf_d = cp[24+ccc];
  }
  __syncthreads();

  #pragma unroll 1
  for (int t = 0; t < LSEG; ++t) {
    #pragma unroll
    for (int s = 0; s < 4; ++s) {
      // =============== P1: (dx2 @ s==0) + L1: X -> H1 ===============
      if (s == 0 && cact) {
        const float third = 1.f/3.f, two3 = 2.f/3.f;
        const int dxo = (ccc & 1)*256 + crow*16 + (ccc >> 1)*4;
        *(float*)((char*)dx2 + dxo)        = cf_b;
        *(float*)((char*)dx2 + dxo + 512)  = fmaf(fmaf(cf_d, third, cf_c), third, cf_b);
        *(float*)((char*)dx2 + dxo + 1024) = fmaf(fmaf(cf_d, two3, cf_c), two3, cf_b);
        *(float*)((char*)dx2 + dxo + 1536) = cf_b + cf_c + cf_d;
        if (t + 1 < LSEG) {
          const float* cp = &coeffs[((size_t)(b0 + crow)*LSEG + (t+1))*32];
          cf_b = cp[8+ccc]; cf_c = cp[16+ccc]; cf_d = cp[24+ccc];
        }
      }
      {
        s16x8 a0 = *(const s16x8*)(Xmem + vbX0);
        s16x8 a1 = *(const s16x8*)(Xmem + vbX1);
        __builtin_amdgcn_s_setprio(1);
        f32x4 acc;
        acc = __builtin_amdgcn_mfma_f32_16x16x32_bf16(a0, Win_f[0], bin4, 0, 0, 0);
        acc = __builtin_amdgcn_mfma_f32_16x16x32_bf16(a1, Win_f[1], acc, 0, 0, 0);
        __builtin_amdgcn_s_setprio(0);
        #pragma unroll
        for (int r = 0; r < 4; ++r) {
          float v = fmaxf(acc[r], 0.f);
          *(unsigned short*)(H1mem + wbH[r]) = (unsigned short)cvt_pk_bf16(v, v);
        }
      }
      __syncthreads();

      // =============== P2: L2: H1 -> H2 ===============
      {
        s16x8 a0 = *(const s16x8*)(H1mem + vbHe);
        s16x8 a1 = *(const s16x8*)(H1mem + vbHo);
        s16x8 a2 = *(const s16x8*)(H1mem + vbHe + 128);
        s16x8 a3 = *(const s16x8*)(H1mem + vbHo + 128);
        __builtin_amdgcn_s_setprio(1);
        f32x4 acc0, acc1 = {};
        acc0 = __builtin_amdgcn_mfma_f32_16x16x32_bf16(a0, Wh0_f[0], bh04, 0, 0, 0);
        acc1 = __builtin_amdgcn_mfma_f32_16x16x32_bf16(a1, Wh0_f[1], acc1, 0, 0, 0);
        acc0 = __builtin_amdgcn_mfma_f32_16x16x32_bf16(a2, Wh0_f[2], acc0, 0, 0, 0);
        acc1 = __builtin_amdgcn_mfma_f32_16x16x32_bf16(a3, Wh0_f[3], acc1, 0, 0, 0);
        __builtin_amdgcn_s_setprio(0);
        f32x4 acc = acc0 + acc1;
        #pragma unroll
        for (int r = 0; r < 4; ++r) {
          float v = fmaxf(acc[r], 0.f);
          *(unsigned short*)(H2mem + wbH[r]) = (unsigned short)cvt_pk_bf16(v, v);
        }
      }
      __syncthreads();

      // =============== P3: L3: H2 -> H1 ===============
      {
        s16x8 a0 = *(const s16x8*)(H2mem + vbHe);
        s16x8 a1 = *(const s16x8*)(H2mem + vbHo);
        s16x8 a2 = *(const s16x8*)(H2mem + vbHe + 128);
        s16x8 a3 = *(const s16x8*)(H2mem + vbHo + 128);
        __builtin_amdgcn_s_setprio(1);
        f32x4 acc0, acc1 = {};
        acc0 = __builtin_amdgcn_mfma_f32_16x16x32_bf16(a0, Wh1_f[0], bh14, 0, 0, 0);
        acc1 = __builtin_amdgcn_mfma_f32_16x16x32_bf16(a1, Wh1_f[1], acc1, 0, 0, 0);
        acc0 = __builtin_amdgcn_mfma_f32_16x16x32_bf16(a2, Wh1_f[2], acc0, 0, 0, 0);
        acc1 = __builtin_amdgcn_mfma_f32_16x16x32_bf16(a3, Wh1_f[3], acc1, 0, 0, 0);
        __builtin_amdgcn_s_setprio(0);
        f32x4 acc = acc0 + acc1;
        #pragma unroll
        for (int r = 0; r < 4; ++r) {
          float v = fmaxf(acc[r], 0.f);
          *(unsigned short*)(H1mem + wbH[r]) = (unsigned short)cvt_pk_bf16(v, v);
        }
      }
      __syncthreads();

      // ========= P4: L4 + tanh + einsum + RK state + X write =========
      {
        f32x4 dxv[4];
        #pragma unroll
        for (int r = 0; r < 4; ++r)
          dxv[r] = *(const f32x4*)((const char*)dx2 + dbx + s*512 + r*16);
        s16x8 a0 = *(const s16x8*)(H1mem + vbHe);
        s16x8 a1 = *(const s16x8*)(H1mem + vbHo);
        s16x8 a2 = *(const s16x8*)(H1mem + vbHe + 128);
        s16x8 a3 = *(const s16x8*)(H1mem + vbHo + 128);
        __builtin_amdgcn_s_setprio(1);
        f32x4 acc[4];
        #pragma unroll
        for (int nt = 0; nt < 4; ++nt)
          acc[nt] = __builtin_amdgcn_mfma_f32_16x16x32_bf16(a0, Wout_f[0][nt], bout4[nt], 0, 0, 0);
        #pragma unroll
        for (int nt = 0; nt < 4; ++nt)
          acc[nt] = __builtin_amdgcn_mfma_f32_16x16x32_bf16(a1, Wout_f[1][nt], acc[nt], 0, 0, 0);
        #pragma unroll
        for (int nt = 0; nt < 4; ++nt)
          acc[nt] = __builtin_amdgcn_mfma_f32_16x16x32_bf16(a2, Wout_f[2][nt], acc[nt], 0, 0, 0);
        #pragma unroll
        for (int nt = 0; nt < 4; ++nt)
          acc[nt] = __builtin_amdgcn_mfma_f32_16x16x32_bf16(a3, Wout_f[3][nt], acc[nt], 0, 0, 0);
        __builtin_amdgcn_s_setprio(0);
        float sums[4];
        #pragma unroll
        for (int r = 0; r < 4; ++r) {
          float sum = 0.f;
          #pragma unroll
          for (int nt = 0; nt < 4; ++nt) {
            // acc is pre-scaled by 2*log2(e): tanh = 1 - 2*rcp(exp2(acc)+1)
            float e2 = __builtin_amdgcn_exp2f(acc[nt][r]);
            float rr = __builtin_amdgcn_rcpf(e2 + 1.f);
            float tv = fmaf(-2.f, rr, 1.f);
            sum = fmaf(tv, dxv[r][nt], sum);
          }
          sums[r] = sum + dpp_xor8(sum);   // full c-sum on both hp halves
        }
        #pragma unroll
        for (int j = 0; j < 2; ++j) {
          const float sum = sums[2*hp + j];
          float znext;
          if (s == 0) {
            k1r[j] = sum;
            zfin[j] = fmaf(0.125f, sum, z0[j]);
            znext   = fmaf(1.f/3.f, sum, z0[j]);
          } else if (s == 1) {
            k2r[j] = sum;
            zfin[j] = fmaf(0.375f, sum, zfin[j]);
            znext   = z0[j] + sum - (1.f/3.f)*k1r[j];
          } else if (s == 2) {
            zfin[j] = fmaf(0.375f, sum, zfin[j]);
            znext   = z0[j] + k1r[j] - k2r[j] + sum;
          } else {
            zfin[j] = fmaf(0.125f, sum, zfin[j]);
            znext   = zfin[j];
            z0[j]   = zfin[j];
          }
          *(unsigned short*)(Xmem + wbX[j]) = (unsigned short)cvt_pk_bf16(znext, znext);
        }
      }
      __syncthreads();
    }
  }

  // ---- readout: stage z0 (fp32) into H1 bytes, then dot W_read ----
  float* ZF = (float*)H1mem;   // plain [16][64] floats
  #pragma unroll
  for (int j = 0; j < 2; ++j)
    ZF[(4*lk + 2*hp + j)*64 + h_own] = z0[j];
  __syncthreads();
  if (tid < 16) {
    float acc = b_read[0];
    for (int h = 0; h < 64; ++h) acc = fmaf(ZF[tid*64 + h], W_read[h], acc);
    out[b0 + tid] = acc;
  }
}

extern "C" void kernel_launch(void* const* d_in, const int* in_sizes, int n_in,
                              void* d_out, int out_size, void* d_ws, size_t ws_size,
                              hipStream_t stream) {
  const float* coeffs = (const float*)d_in[0];
  const float* W_init = (const float*)d_in[1];
  const float* b_init = (const float*)d_in[2];
  const float* W_in   = (const float*)d_in[3];
  const float* b_in   = (const float*)d_in[4];
  const float* W_h    = (const float*)d_in[5];
  const float* b_h    = (const float*)d_in[6];
  const float* W_out  = (const float*)d_in[7];
  const float* b_out  = (const float*)d_in[8];
  const float* W_read = (const float*)d_in[9];
  const float* b_read = (const float*)d_in[10];
  float* out = (float*)d_out;

  cde_kernel<<<dim3(256), dim3(512), 0, stream>>>(
      coeffs, W_init, b_init, W_in, b_in, W_h, b_h, W_out, b_out,
      W_read, b_read, out);
}